// Round 4
// baseline (570.926 us; speedup 1.0000x reference)
//
#include <hip/hip_runtime.h>
#include <hip/hip_bf16.h>
#include <math.h>

// GAT 2-layer. Round 4: h1 stored as bf16 (halves gather bytes), kg1
// restructured to 2 edges per wave (half-wave per edge, 4 ch/lane) with x4
// unrolled gather pipeline. Scores stay fp32. CSR build: rank-based scatter.

typedef unsigned short u16;

__device__ __forceinline__ float leaky02(float e) { return e >= 0.f ? e : 0.2f * e; }
__device__ __forceinline__ float eluf(float v) { return v > 0.f ? v : expm1f(v); }
__device__ __forceinline__ u16 f2bf(float f) {
    unsigned int u = __float_as_uint(f);
    u += 0x7fff + ((u >> 16) & 1);          // RNE
    return (u16)(u >> 16);
}
__device__ __forceinline__ float bf2f(u16 u) {
    return __uint_as_float(((unsigned int)u) << 16);
}

// ---------------- K1: h1 = x @ W1  (+ a_s1/a_d1), bf16 h1 out --------------
__global__ __launch_bounds__(256) void k1_gemm(
    const float* __restrict__ x, const float* __restrict__ W1,
    const float* __restrict__ att_s, const float* __restrict__ att_d,
    u16* __restrict__ h1b, float* __restrict__ as1, float* __restrict__ ad1,
    int N)
{
    __shared__ float xs[128 * 64];   // [row][k] chunk
    __shared__ float wsh[64 * 128];  // [k][col] chunk
    const int tid = threadIdx.x;
    const int row0 = blockIdx.x * 128;
    const int tx = tid & 15, ty = tid >> 4;
    const int c0 = tx * 8;
    const int ty8 = ty * 8;

    float acc[8][8];
    #pragma unroll
    for (int i = 0; i < 8; ++i)
        #pragma unroll
        for (int j = 0; j < 8; ++j) acc[i][j] = 0.f;

    for (int kc = 0; kc < 2; ++kc) {
        #pragma unroll
        for (int i = 0; i < 8; ++i) {
            int fi = (tid + i * 256) * 4;
            int r = fi >> 6;
            int k = fi & 63;
            float4 v = {0.f, 0.f, 0.f, 0.f};
            if (row0 + r < N)
                v = *(const float4*)&x[(size_t)(row0 + r) * 128 + kc * 64 + k];
            *(float4*)&xs[r * 64 + k] = v;
        }
        const float* wsrc = W1 + kc * 64 * 128;
        #pragma unroll
        for (int i = 0; i < 8; ++i) {
            int fi = (tid + i * 256) * 4;
            *(float4*)&wsh[fi] = *(const float4*)&wsrc[fi];
        }
        __syncthreads();

        #pragma unroll 2
        for (int k = 0; k < 64; k += 4) {
            float4 xa[8];
            float4 wa[4][2];
            #pragma unroll
            for (int i = 0; i < 8; ++i)
                xa[i] = *(const float4*)&xs[(ty8 + i) * 64 + k];
            #pragma unroll
            for (int kk = 0; kk < 4; ++kk) {
                wa[kk][0] = *(const float4*)&wsh[(k + kk) * 128 + c0];
                wa[kk][1] = *(const float4*)&wsh[(k + kk) * 128 + c0 + 4];
            }
            #pragma unroll
            for (int i = 0; i < 8; ++i) {
                float xv[4] = {xa[i].x, xa[i].y, xa[i].z, xa[i].w};
                #pragma unroll
                for (int kk = 0; kk < 4; ++kk) {
                    acc[i][0] = fmaf(xv[kk], wa[kk][0].x, acc[i][0]);
                    acc[i][1] = fmaf(xv[kk], wa[kk][0].y, acc[i][1]);
                    acc[i][2] = fmaf(xv[kk], wa[kk][0].z, acc[i][2]);
                    acc[i][3] = fmaf(xv[kk], wa[kk][0].w, acc[i][3]);
                    acc[i][4] = fmaf(xv[kk], wa[kk][1].x, acc[i][4]);
                    acc[i][5] = fmaf(xv[kk], wa[kk][1].y, acc[i][5]);
                    acc[i][6] = fmaf(xv[kk], wa[kk][1].z, acc[i][6]);
                    acc[i][7] = fmaf(xv[kk], wa[kk][1].w, acc[i][7]);
                }
            }
        }
        __syncthreads();
    }

    const int head = tx >> 2;
    const int cbase = c0 & 31;
    float asv[8], adv[8];
    #pragma unroll
    for (int i = 0; i < 8; ++i) {
        float s = 0.f, d = 0.f;
        #pragma unroll
        for (int j = 0; j < 8; ++j) {
            float av = acc[i][j];
            s = fmaf(av, att_s[head * 32 + cbase + j], s);
            d = fmaf(av, att_d[head * 32 + cbase + j], d);
        }
        asv[i] = s; adv[i] = d;
    }
    #pragma unroll
    for (int i = 0; i < 8; ++i) {
        asv[i] += __shfl_xor(asv[i], 1); asv[i] += __shfl_xor(asv[i], 2);
        adv[i] += __shfl_xor(adv[i], 1); adv[i] += __shfl_xor(adv[i], 2);
    }
    #pragma unroll
    for (int i = 0; i < 8; ++i) {
        int row = row0 + ty8 + i;
        if (row >= N) continue;
        union { u16 us[8]; uint4 v; } pk;
        #pragma unroll
        for (int j = 0; j < 8; ++j) pk.us[j] = f2bf(acc[i][j]);
        *(uint4*)&h1b[(size_t)row * 128 + c0] = pk.v;
        if ((tx & 3) == 0) {
            as1[row * 4 + head] = asv[i];
            ad1[row * 4 + head] = adv[i];
        }
    }
}

// ---------------- CSR build ------------------------------------------------
__global__ __launch_bounds__(256) void khist(
    const int* __restrict__ ei, int* __restrict__ deg,
    int* __restrict__ rank, int E)
{
    int e = blockIdx.x * 256 + threadIdx.x;
    if (e < E) rank[e] = atomicAdd(&deg[ei[E + e]], 1);
}

__global__ __launch_bounds__(256) void kscan1(
    const int* __restrict__ deg, int* __restrict__ rowptr,
    int* __restrict__ bsum, int N)
{
    __shared__ int lds[256];
    const int t = threadIdx.x;
    const int base = blockIdx.x * 1024 + t * 4;
    int v[4];
    int s = 0;
    #pragma unroll
    for (int j = 0; j < 4; ++j) {
        v[j] = (base + j < N) ? deg[base + j] : 0;
        s += v[j];
    }
    lds[t] = s;
    __syncthreads();
    for (int off = 1; off < 256; off <<= 1) {
        int y = (t >= off) ? lds[t - off] : 0;
        __syncthreads();
        lds[t] += y;
        __syncthreads();
    }
    int run = lds[t] - s;
    #pragma unroll
    for (int j = 0; j < 4; ++j) {
        if (base + j < N) rowptr[base + j] = run;
        run += v[j];
    }
    if (t == 255) bsum[blockIdx.x] = lds[255];
}

__global__ __launch_bounds__(128) void kscan2(int* __restrict__ bsum, int NB)
{
    __shared__ int lds[128];
    const int t = threadIdx.x;
    int v = (t < NB) ? bsum[t] : 0;
    lds[t] = v;
    __syncthreads();
    for (int off = 1; off < 128; off <<= 1) {
        int y = (t >= off) ? lds[t - off] : 0;
        __syncthreads();
        lds[t] += y;
        __syncthreads();
    }
    if (t < NB) bsum[t] = lds[t] - v;
}

__global__ __launch_bounds__(256) void kscan3(
    int* __restrict__ rowptr, const int* __restrict__ bsum, int N, int E)
{
    const int base = blockIdx.x * 1024 + threadIdx.x * 4;
    const int add = bsum[blockIdx.x];
    #pragma unroll
    for (int j = 0; j < 4; ++j)
        if (base + j < N) rowptr[base + j] += add;
    if (blockIdx.x == 0 && threadIdx.x == 0) rowptr[N] = E;
}

__global__ __launch_bounds__(256) void kscatter(
    const int* __restrict__ ei, const int* __restrict__ rowptr,
    const int* __restrict__ rank, int* __restrict__ colidx, int E)
{
    int e = blockIdx.x * 256 + threadIdx.x;
    if (e >= E) return;
    colidx[rowptr[ei[E + e]] + rank[e]] = ei[e];
}

// ---------------- KG1: layer-1 gather + elu + fused x2@W2 ------------------
// One wave per node; 2 edges processed concurrently (half-wave per edge,
// 4 channels per lane, bf16 h1). x4 unroll per half = 8 gathers in flight.
__global__ __launch_bounds__(256) void kg1(
    const int* __restrict__ rowptr, const int* __restrict__ colidx,
    const u16* __restrict__ h1b, const float* __restrict__ as1,
    const float* __restrict__ ad1, const float* __restrict__ b1,
    const float* __restrict__ W2, const float* __restrict__ ats2,
    const float* __restrict__ atd2,
    float* __restrict__ h2, float* __restrict__ as2, float* __restrict__ ad2,
    int N)
{
    const int d = blockIdx.x * 4 + (threadIdx.x >> 6);
    if (d >= N) return;
    const int lane = threadIdx.x & 63;
    const int half = lane >> 5;
    const int q = lane & 31;
    const int c = q * 4;          // channels c..c+3
    const int head = q >> 3;

    const float ad_d = ad1[d * 4 + head];
    const float as_d = as1[d * 4 + head];

    float acc0 = 0.f, acc1 = 0.f, acc2 = 0.f, acc3 = 0.f, den = 0.f;

    const int i0 = __builtin_amdgcn_readfirstlane(rowptr[d]);
    const int i1 = __builtin_amdgcn_readfirstlane(rowptr[d + 1]);
    int i = i0 + half;
    for (; i + 6 < i1; i += 8) {           // 4 edges for this half
        int s0 = colidx[i];
        int s1 = colidx[i + 2];
        int s2 = colidx[i + 4];
        int s3 = colidx[i + 6];
        float a0 = as1[s0 * 4 + head];
        float a1 = as1[s1 * 4 + head];
        float a2 = as1[s2 * 4 + head];
        float a3 = as1[s3 * 4 + head];
        ushort4 v0 = *(const ushort4*)&h1b[(s0 << 7) + c];
        ushort4 v1 = *(const ushort4*)&h1b[(s1 << 7) + c];
        ushort4 v2 = *(const ushort4*)&h1b[(s2 << 7) + c];
        ushort4 v3 = *(const ushort4*)&h1b[(s3 << 7) + c];
        float w0 = __expf(leaky02(a0 + ad_d));
        float w1 = __expf(leaky02(a1 + ad_d));
        float w2 = __expf(leaky02(a2 + ad_d));
        float w3 = __expf(leaky02(a3 + ad_d));
        acc0 = fmaf(w0, bf2f(v0.x), acc0); acc1 = fmaf(w0, bf2f(v0.y), acc1);
        acc2 = fmaf(w0, bf2f(v0.z), acc2); acc3 = fmaf(w0, bf2f(v0.w), acc3);
        acc0 = fmaf(w1, bf2f(v1.x), acc0); acc1 = fmaf(w1, bf2f(v1.y), acc1);
        acc2 = fmaf(w1, bf2f(v1.z), acc2); acc3 = fmaf(w1, bf2f(v1.w), acc3);
        acc0 = fmaf(w2, bf2f(v2.x), acc0); acc1 = fmaf(w2, bf2f(v2.y), acc1);
        acc2 = fmaf(w2, bf2f(v2.z), acc2); acc3 = fmaf(w2, bf2f(v2.w), acc3);
        acc0 = fmaf(w3, bf2f(v3.x), acc0); acc1 = fmaf(w3, bf2f(v3.y), acc1);
        acc2 = fmaf(w3, bf2f(v3.z), acc2); acc3 = fmaf(w3, bf2f(v3.w), acc3);
        den += (w0 + w1) + (w2 + w3);
    }
    for (; i < i1; i += 2) {
        int s = colidx[i];
        float a = as1[s * 4 + head];
        ushort4 v = *(const ushort4*)&h1b[(s << 7) + c];
        float w = __expf(leaky02(a + ad_d));
        acc0 = fmaf(w, bf2f(v.x), acc0); acc1 = fmaf(w, bf2f(v.y), acc1);
        acc2 = fmaf(w, bf2f(v.z), acc2); acc3 = fmaf(w, bf2f(v.w), acc3);
        den += w;
    }

    // merge the two halves (after this, both halves hold identical sums)
    acc0 += __shfl_xor(acc0, 32); acc1 += __shfl_xor(acc1, 32);
    acc2 += __shfl_xor(acc2, 32); acc3 += __shfl_xor(acc3, 32);
    den  += __shfl_xor(den, 32);

    // self contribution (added once per half-duplicated channel set)
    const float wself = __expf(leaky02(as_d + ad_d));
    ushort4 hd = *(const ushort4*)&h1b[(d << 7) + c];
    acc0 = fmaf(wself, bf2f(hd.x), acc0);
    acc1 = fmaf(wself, bf2f(hd.y), acc1);
    acc2 = fmaf(wself, bf2f(hd.z), acc2);
    acc3 = fmaf(wself, bf2f(hd.w), acc3);
    den += wself;

    const float inv = 1.f / den;
    const float4 bv = *(const float4*)&b1[c];
    const float x0 = eluf(fmaf(acc0, inv, bv.x));
    const float x1 = eluf(fmaf(acc1, inv, bv.y));
    const float x2 = eluf(fmaf(acc2, inv, bv.z));
    const float x3 = eluf(fmaf(acc3, inv, bv.w));

    // partial h2[j] over this lane's 4 channels
    float p[16];
    #pragma unroll
    for (int qq = 0; qq < 4; ++qq) {
        float4 wr0 = *(const float4*)&W2[(c + 0) * 16 + qq * 4];
        float4 wr1 = *(const float4*)&W2[(c + 1) * 16 + qq * 4];
        float4 wr2 = *(const float4*)&W2[(c + 2) * 16 + qq * 4];
        float4 wr3 = *(const float4*)&W2[(c + 3) * 16 + qq * 4];
        p[qq * 4 + 0] = fmaf(x0, wr0.x, fmaf(x1, wr1.x, fmaf(x2, wr2.x, x3 * wr3.x)));
        p[qq * 4 + 1] = fmaf(x0, wr0.y, fmaf(x1, wr1.y, fmaf(x2, wr2.y, x3 * wr3.y)));
        p[qq * 4 + 2] = fmaf(x0, wr0.z, fmaf(x1, wr1.z, fmaf(x2, wr2.z, x3 * wr3.z)));
        p[qq * 4 + 3] = fmaf(x0, wr0.w, fmaf(x1, wr1.w, fmaf(x2, wr2.w, x3 * wr3.w)));
    }
    // butterfly over 32 lanes (each half independently -> identical results)
    #pragma unroll
    for (int m = 1; m < 32; m <<= 1) {
        #pragma unroll
        for (int j = 0; j < 16; ++j) p[j] += __shfl_xor(p[j], m);
    }
    float s2 = 0.f, d2 = 0.f;
    #pragma unroll
    for (int j = 0; j < 16; ++j) {
        s2 = fmaf(p[j], ats2[j], s2);
        d2 = fmaf(p[j], atd2[j], d2);
    }
    if (lane == 0) { as2[d] = s2; ad2[d] = d2; }
    if (lane < 4) {
        float4 hv = {p[lane * 4 + 0], p[lane * 4 + 1],
                     p[lane * 4 + 2], p[lane * 4 + 3]};
        *(float4*)&h2[(d << 4) + lane * 4] = hv;
    }
}

// ---------------- KG2: layer-2 gather -> out -------------------------------
__global__ __launch_bounds__(256) void kg2(
    const int* __restrict__ rowptr, const int* __restrict__ colidx,
    const float* __restrict__ h2, const float* __restrict__ as2,
    const float* __restrict__ ad2, const float* __restrict__ b2,
    float* __restrict__ out, int N)
{
    const int d = blockIdx.x * 4 + (threadIdx.x >> 6);
    if (d >= N) return;
    const int lane = threadIdx.x & 63;
    const int j = lane & 15, g = lane >> 4;

    const float ad_d = ad2[d];
    float acc = 0.f, den = 0.f;
    const int i0 = __builtin_amdgcn_readfirstlane(rowptr[d]);
    const int i1 = __builtin_amdgcn_readfirstlane(rowptr[d + 1]);
    int i = i0 + g;
    for (; i + 4 < i1; i += 8) {
        int s0 = colidx[i];
        int s1 = colidx[i + 4];
        float a0 = as2[s0];
        float a1 = as2[s1];
        float v0 = h2[(s0 << 4) + j];
        float v1 = h2[(s1 << 4) + j];
        float w0 = __expf(leaky02(a0 + ad_d));
        float w1 = __expf(leaky02(a1 + ad_d));
        acc = fmaf(w0, v0, acc);
        acc = fmaf(w1, v1, acc);
        den += w0 + w1;
    }
    for (; i < i1; i += 4) {
        int s = colidx[i];
        float w = __expf(leaky02(as2[s] + ad_d));
        acc = fmaf(w, h2[(s << 4) + j], acc);
        den += w;
    }
    acc += __shfl_xor(acc, 16); acc += __shfl_xor(acc, 32);
    den += __shfl_xor(den, 16); den += __shfl_xor(den, 32);

    const float wself = __expf(leaky02(as2[d] + ad_d));
    acc = fmaf(wself, h2[(d << 4) + j], acc);
    den += wself;
    if (g == 0) out[(d << 4) + j] = acc / den + b2[j];
}

extern "C" void kernel_launch(void* const* d_in, const int* in_sizes, int n_in,
                              void* d_out, int out_size, void* d_ws, size_t ws_size,
                              hipStream_t stream) {
    const float* x    = (const float*)d_in[0];
    const int*   ei   = (const int*)d_in[1];
    const float* W1   = (const float*)d_in[2];
    const float* ats1 = (const float*)d_in[3];
    const float* atd1 = (const float*)d_in[4];
    const float* b1   = (const float*)d_in[5];
    const float* W2   = (const float*)d_in[6];
    const float* ats2 = (const float*)d_in[7];
    const float* atd2 = (const float*)d_in[8];
    const float* b2   = (const float*)d_in[9];
    float* out = (float*)d_out;
    const int N = in_sizes[0] / 128;
    const int E = in_sizes[1] / 2;

    u16* h1b   = (u16*)d_ws;                        // 128N u16 = 64N floats
    float* fb  = (float*)(h1b + (size_t)N * 128);
    float* as1 = fb;                                // 4N
    float* ad1 = as1 + (size_t)N * 4;               // 4N
    float* h2  = ad1 + (size_t)N * 4;               // 16N
    float* as2 = h2 + (size_t)N * 16;               // N
    float* ad2 = as2 + N;                           // N
    int* deg    = (int*)(ad2 + N);                  // N
    int* rowptr = deg + N;                          // N+1
    int* bsum   = rowptr + N + 1;                   // 128
    int* colidx = bsum + 128;                       // E
    int* rank   = colidx + E;                       // E

    const int NB = (N + 1023) / 1024;

    hipMemsetAsync(deg, 0, (size_t)N * sizeof(int), stream);

    hipLaunchKernelGGL(k1_gemm, dim3((N + 127) / 128), dim3(256), 0, stream,
                       x, W1, ats1, atd1, h1b, as1, ad1, N);
    hipLaunchKernelGGL(khist, dim3((E + 255) / 256), dim3(256), 0, stream,
                       ei, deg, rank, E);
    hipLaunchKernelGGL(kscan1, dim3(NB), dim3(256), 0, stream,
                       deg, rowptr, bsum, N);
    hipLaunchKernelGGL(kscan2, dim3(1), dim3(128), 0, stream, bsum, NB);
    hipLaunchKernelGGL(kscan3, dim3(NB), dim3(256), 0, stream,
                       rowptr, bsum, N, E);
    hipLaunchKernelGGL(kscatter, dim3((E + 255) / 256), dim3(256), 0, stream,
                       ei, rowptr, rank, colidx, E);
    hipLaunchKernelGGL(kg1, dim3((N + 3) / 4), dim3(256), 0, stream,
                       rowptr, colidx, h1b, as1, ad1, b1, W2, ats2, atd2,
                       h2, as2, ad2, N);
    hipLaunchKernelGGL(kg2, dim3((N + 3) / 4), dim3(256), 0, stream,
                       rowptr, colidx, h2, as2, ad2, b2, out, N);
}

// Round 5
// 429.096 us; speedup vs baseline: 1.3305x; 1.3305x over previous
//
#include <hip/hip_runtime.h>
#include <hip/hip_bf16.h>
#include <math.h>

// GAT 2-layer. Round 5: kg1 back to full-wave-per-edge (bf16 h1, ushort2
// per lane, x8 unroll, wave-uniform colidx); epilogue folded via
// u=W2@ats2 / v=W2@atd2 so kg1 only writes x2(bf16)+as2/ad2; h2=x2@W2 done
// by a dense MFMA kernel (16x16x32 bf16). CSR build: rank-based scatter.

typedef unsigned short u16;
typedef unsigned int u32;
typedef __attribute__((ext_vector_type(8))) short bf16x8;
typedef __attribute__((ext_vector_type(4))) float f32x4;

__device__ __forceinline__ float leaky02(float e) { return e >= 0.f ? e : 0.2f * e; }
__device__ __forceinline__ float eluf(float v) { return v > 0.f ? v : expm1f(v); }
__device__ __forceinline__ u16 f2bf(float f) {
    u32 u = __float_as_uint(f);
    u += 0x7fff + ((u >> 16) & 1);          // RNE
    return (u16)(u >> 16);
}
__device__ __forceinline__ float bf2f(u16 u) {
    return __uint_as_float(((u32)u) << 16);
}

// ---------------- K1: h1 = x @ W1  (+ a_s1/a_d1), bf16 h1 out --------------
__global__ __launch_bounds__(256) void k1_gemm(
    const float* __restrict__ x, const float* __restrict__ W1,
    const float* __restrict__ att_s, const float* __restrict__ att_d,
    u16* __restrict__ h1b, float* __restrict__ as1, float* __restrict__ ad1,
    int N)
{
    __shared__ float xs[128 * 64];   // [row][k] chunk
    __shared__ float wsh[64 * 128];  // [k][col] chunk
    const int tid = threadIdx.x;
    const int row0 = blockIdx.x * 128;
    const int tx = tid & 15, ty = tid >> 4;
    const int c0 = tx * 8;
    const int ty8 = ty * 8;

    float acc[8][8];
    #pragma unroll
    for (int i = 0; i < 8; ++i)
        #pragma unroll
        for (int j = 0; j < 8; ++j) acc[i][j] = 0.f;

    for (int kc = 0; kc < 2; ++kc) {
        #pragma unroll
        for (int i = 0; i < 8; ++i) {
            int fi = (tid + i * 256) * 4;
            int r = fi >> 6;
            int k = fi & 63;
            float4 v = {0.f, 0.f, 0.f, 0.f};
            if (row0 + r < N)
                v = *(const float4*)&x[(size_t)(row0 + r) * 128 + kc * 64 + k];
            *(float4*)&xs[r * 64 + k] = v;
        }
        const float* wsrc = W1 + kc * 64 * 128;
        #pragma unroll
        for (int i = 0; i < 8; ++i) {
            int fi = (tid + i * 256) * 4;
            *(float4*)&wsh[fi] = *(const float4*)&wsrc[fi];
        }
        __syncthreads();

        #pragma unroll 2
        for (int k = 0; k < 64; k += 4) {
            float4 xa[8];
            float4 wa[4][2];
            #pragma unroll
            for (int i = 0; i < 8; ++i)
                xa[i] = *(const float4*)&xs[(ty8 + i) * 64 + k];
            #pragma unroll
            for (int kk = 0; kk < 4; ++kk) {
                wa[kk][0] = *(const float4*)&wsh[(k + kk) * 128 + c0];
                wa[kk][1] = *(const float4*)&wsh[(k + kk) * 128 + c0 + 4];
            }
            #pragma unroll
            for (int i = 0; i < 8; ++i) {
                float xv[4] = {xa[i].x, xa[i].y, xa[i].z, xa[i].w};
                #pragma unroll
                for (int kk = 0; kk < 4; ++kk) {
                    acc[i][0] = fmaf(xv[kk], wa[kk][0].x, acc[i][0]);
                    acc[i][1] = fmaf(xv[kk], wa[kk][0].y, acc[i][1]);
                    acc[i][2] = fmaf(xv[kk], wa[kk][0].z, acc[i][2]);
                    acc[i][3] = fmaf(xv[kk], wa[kk][0].w, acc[i][3]);
                    acc[i][4] = fmaf(xv[kk], wa[kk][1].x, acc[i][4]);
                    acc[i][5] = fmaf(xv[kk], wa[kk][1].y, acc[i][5]);
                    acc[i][6] = fmaf(xv[kk], wa[kk][1].z, acc[i][6]);
                    acc[i][7] = fmaf(xv[kk], wa[kk][1].w, acc[i][7]);
                }
            }
        }
        __syncthreads();
    }

    const int head = tx >> 2;
    const int cbase = c0 & 31;
    float asv[8], adv[8];
    #pragma unroll
    for (int i = 0; i < 8; ++i) {
        float s = 0.f, d = 0.f;
        #pragma unroll
        for (int j = 0; j < 8; ++j) {
            float av = acc[i][j];
            s = fmaf(av, att_s[head * 32 + cbase + j], s);
            d = fmaf(av, att_d[head * 32 + cbase + j], d);
        }
        asv[i] = s; adv[i] = d;
    }
    #pragma unroll
    for (int i = 0; i < 8; ++i) {
        asv[i] += __shfl_xor(asv[i], 1); asv[i] += __shfl_xor(asv[i], 2);
        adv[i] += __shfl_xor(adv[i], 1); adv[i] += __shfl_xor(adv[i], 2);
    }
    #pragma unroll
    for (int i = 0; i < 8; ++i) {
        int row = row0 + ty8 + i;
        if (row >= N) continue;
        union { u16 us[8]; uint4 v; } pk;
        #pragma unroll
        for (int j = 0; j < 8; ++j) pk.us[j] = f2bf(acc[i][j]);
        *(uint4*)&h1b[(size_t)row * 128 + c0] = pk.v;
        if ((tx & 3) == 0) {
            as1[row * 4 + head] = asv[i];
            ad1[row * 4 + head] = adv[i];
        }
    }
}

// ---------------- kprep: u = W2@ats2, v = W2@atd2, w2tb = W2^T (bf16) ------
__global__ __launch_bounds__(128) void kprep(
    const float* __restrict__ W2, const float* __restrict__ ats2,
    const float* __restrict__ atd2,
    float* __restrict__ u, float* __restrict__ v, u16* __restrict__ w2tb)
{
    const int c = threadIdx.x;      // 0..127
    float su = 0.f, sv = 0.f;
    #pragma unroll
    for (int j = 0; j < 16; ++j) {
        float w = W2[c * 16 + j];
        su = fmaf(w, ats2[j], su);
        sv = fmaf(w, atd2[j], sv);
        w2tb[j * 128 + c] = f2bf(w);   // transposed: [j][c]
    }
    u[c] = su; v[c] = sv;
}

// ---------------- CSR build ------------------------------------------------
__global__ __launch_bounds__(256) void khist(
    const int* __restrict__ ei, int* __restrict__ deg,
    int* __restrict__ rank, int E)
{
    int e = blockIdx.x * 256 + threadIdx.x;
    if (e < E) rank[e] = atomicAdd(&deg[ei[E + e]], 1);
}

__global__ __launch_bounds__(256) void kscan1(
    const int* __restrict__ deg, int* __restrict__ rowptr,
    int* __restrict__ bsum, int N)
{
    __shared__ int lds[256];
    const int t = threadIdx.x;
    const int base = blockIdx.x * 1024 + t * 4;
    int v[4];
    int s = 0;
    #pragma unroll
    for (int j = 0; j < 4; ++j) {
        v[j] = (base + j < N) ? deg[base + j] : 0;
        s += v[j];
    }
    lds[t] = s;
    __syncthreads();
    for (int off = 1; off < 256; off <<= 1) {
        int y = (t >= off) ? lds[t - off] : 0;
        __syncthreads();
        lds[t] += y;
        __syncthreads();
    }
    int run = lds[t] - s;
    #pragma unroll
    for (int j = 0; j < 4; ++j) {
        if (base + j < N) rowptr[base + j] = run;
        run += v[j];
    }
    if (t == 255) bsum[blockIdx.x] = lds[255];
}

__global__ __launch_bounds__(128) void kscan2(int* __restrict__ bsum, int NB)
{
    __shared__ int lds[128];
    const int t = threadIdx.x;
    int v = (t < NB) ? bsum[t] : 0;
    lds[t] = v;
    __syncthreads();
    for (int off = 1; off < 128; off <<= 1) {
        int y = (t >= off) ? lds[t - off] : 0;
        __syncthreads();
        lds[t] += y;
        __syncthreads();
    }
    if (t < NB) bsum[t] = lds[t] - v;
}

__global__ __launch_bounds__(256) void kscan3(
    int* __restrict__ rowptr, const int* __restrict__ bsum, int N, int E)
{
    const int base = blockIdx.x * 1024 + threadIdx.x * 4;
    const int add = bsum[blockIdx.x];
    #pragma unroll
    for (int j = 0; j < 4; ++j)
        if (base + j < N) rowptr[base + j] += add;
    if (blockIdx.x == 0 && threadIdx.x == 0) rowptr[N] = E;
}

__global__ __launch_bounds__(256) void kscatter(
    const int* __restrict__ ei, const int* __restrict__ rowptr,
    const int* __restrict__ rank, int* __restrict__ colidx, int E)
{
    int e = blockIdx.x * 256 + threadIdx.x;
    if (e >= E) return;
    colidx[rowptr[ei[E + e]] + rank[e]] = ei[e];
}

// ---------------- KG1: layer-1 gather + elu -> x2 (bf16) + as2/ad2 ---------
// One wave per node, one edge at a time (wave-uniform colidx), 2 ch/lane
// bf16 (256 B/edge), x8 unrolled gather pipeline. Epilogue: folded dots
// with u/v (no transpose, no W2 loads).
__global__ __launch_bounds__(256) void kg1(
    const int* __restrict__ rowptr, const int* __restrict__ colidx,
    const u16* __restrict__ h1b, const float* __restrict__ as1,
    const float* __restrict__ ad1, const float* __restrict__ b1,
    const float* __restrict__ u, const float* __restrict__ v,
    u16* __restrict__ x2b, float* __restrict__ as2, float* __restrict__ ad2,
    int N)
{
    const int d = blockIdx.x * 4 + (threadIdx.x >> 6);
    if (d >= N) return;
    const int lane = threadIdx.x & 63;
    const int c = lane * 2;
    const int head = lane >> 4;

    const float ad_d = ad1[d * 4 + head];
    const float as_d = as1[d * 4 + head];

    // self contribution
    const float wself = __expf(leaky02(as_d + ad_d));
    u32 hd = *(const u32*)&h1b[(d << 7) + c];
    float accx = wself * bf2f((u16)hd);
    float accy = wself * bf2f((u16)(hd >> 16));
    float den = wself;

    const int i0 = __builtin_amdgcn_readfirstlane(rowptr[d]);
    const int i1 = __builtin_amdgcn_readfirstlane(rowptr[d + 1]);
    int i = i0;
    for (; i + 8 <= i1; i += 8) {
        int s0 = colidx[i + 0];
        int s1 = colidx[i + 1];
        int s2 = colidx[i + 2];
        int s3 = colidx[i + 3];
        int s4 = colidx[i + 4];
        int s5 = colidx[i + 5];
        int s6 = colidx[i + 6];
        int s7 = colidx[i + 7];
        float a0 = as1[s0 * 4 + head];
        float a1 = as1[s1 * 4 + head];
        float a2 = as1[s2 * 4 + head];
        float a3 = as1[s3 * 4 + head];
        float a4 = as1[s4 * 4 + head];
        float a5 = as1[s5 * 4 + head];
        float a6 = as1[s6 * 4 + head];
        float a7 = as1[s7 * 4 + head];
        u32 v0 = *(const u32*)&h1b[(s0 << 7) + c];
        u32 v1 = *(const u32*)&h1b[(s1 << 7) + c];
        u32 v2 = *(const u32*)&h1b[(s2 << 7) + c];
        u32 v3 = *(const u32*)&h1b[(s3 << 7) + c];
        u32 v4 = *(const u32*)&h1b[(s4 << 7) + c];
        u32 v5 = *(const u32*)&h1b[(s5 << 7) + c];
        u32 v6 = *(const u32*)&h1b[(s6 << 7) + c];
        u32 v7 = *(const u32*)&h1b[(s7 << 7) + c];
        float w0 = __expf(leaky02(a0 + ad_d));
        float w1 = __expf(leaky02(a1 + ad_d));
        float w2 = __expf(leaky02(a2 + ad_d));
        float w3 = __expf(leaky02(a3 + ad_d));
        float w4 = __expf(leaky02(a4 + ad_d));
        float w5 = __expf(leaky02(a5 + ad_d));
        float w6 = __expf(leaky02(a6 + ad_d));
        float w7 = __expf(leaky02(a7 + ad_d));
        accx = fmaf(w0, bf2f((u16)v0), accx); accy = fmaf(w0, bf2f((u16)(v0 >> 16)), accy);
        accx = fmaf(w1, bf2f((u16)v1), accx); accy = fmaf(w1, bf2f((u16)(v1 >> 16)), accy);
        accx = fmaf(w2, bf2f((u16)v2), accx); accy = fmaf(w2, bf2f((u16)(v2 >> 16)), accy);
        accx = fmaf(w3, bf2f((u16)v3), accx); accy = fmaf(w3, bf2f((u16)(v3 >> 16)), accy);
        accx = fmaf(w4, bf2f((u16)v4), accx); accy = fmaf(w4, bf2f((u16)(v4 >> 16)), accy);
        accx = fmaf(w5, bf2f((u16)v5), accx); accy = fmaf(w5, bf2f((u16)(v5 >> 16)), accy);
        accx = fmaf(w6, bf2f((u16)v6), accx); accy = fmaf(w6, bf2f((u16)(v6 >> 16)), accy);
        accx = fmaf(w7, bf2f((u16)v7), accx); accy = fmaf(w7, bf2f((u16)(v7 >> 16)), accy);
        den += ((w0 + w1) + (w2 + w3)) + ((w4 + w5) + (w6 + w7));
    }
    for (; i < i1; ++i) {
        int s = colidx[i];
        float a = as1[s * 4 + head];
        u32 hv = *(const u32*)&h1b[(s << 7) + c];
        float w = __expf(leaky02(a + ad_d));
        accx = fmaf(w, bf2f((u16)hv), accx);
        accy = fmaf(w, bf2f((u16)(hv >> 16)), accy);
        den += w;
    }

    const float inv = 1.f / den;
    const float2 bv = *(const float2*)&b1[c];
    const float x2a = eluf(fmaf(accx, inv, bv.x));
    const float x2c = eluf(fmaf(accy, inv, bv.y));

    // store x2 (bf16, 256 B per wave, coalesced)
    u32 pk = ((u32)f2bf(x2c) << 16) | (u32)f2bf(x2a);
    *(u32*)&x2b[(d << 7) + c] = pk;

    // folded attention dots: as2 = x2 . u, ad2 = x2 . v
    const float2 uv = *(const float2*)&u[c];
    const float2 vv = *(const float2*)&v[c];
    float sA = fmaf(x2a, uv.x, x2c * uv.y);
    float sB = fmaf(x2a, vv.x, x2c * vv.y);
    #pragma unroll
    for (int m = 1; m < 64; m <<= 1) {
        sA += __shfl_xor(sA, m);
        sB += __shfl_xor(sB, m);
    }
    if (lane == 0) { as2[d] = sA; ad2[d] = sB; }
}

// ---------------- KH2: h2 = x2 @ W2 via MFMA 16x16x32 bf16 -----------------
// One wave per 16 nodes; B (W2^T bf16) held in regs, 4 MFMAs over K=128.
__global__ __launch_bounds__(256) void kh2(
    const u16* __restrict__ x2b, const u16* __restrict__ w2tb,
    float* __restrict__ h2, int N)
{
    const int wv = threadIdx.x >> 6, lane = threadIdx.x & 63;
    const int n0 = blockIdx.x * 64 + wv * 16;
    if (n0 >= N) return;
    const int m = lane & 15;         // A row / D col
    const int kq = lane >> 2 >> 2;   // lane>>4: k-quad
    // B frag: B[k = q*32 + kq*8 + j][n = m]  from w2tb[n][k]
    bf16x8 bfr[4];
    #pragma unroll
    for (int q = 0; q < 4; ++q)
        bfr[q] = *(const bf16x8*)&w2tb[m * 128 + q * 32 + kq * 8];

    const u16* arow = &x2b[((size_t)(n0 + m) << 7) + kq * 8];
    f32x4 acc = {0.f, 0.f, 0.f, 0.f};
    #pragma unroll
    for (int q = 0; q < 4; ++q) {
        bf16x8 af = *(const bf16x8*)&arow[q * 32];
        acc = __builtin_amdgcn_mfma_f32_16x16x32_bf16(af, bfr[q], acc, 0, 0, 0);
    }
    // D: col = m, row = kq*4 + r
    #pragma unroll
    for (int r = 0; r < 4; ++r)
        h2[(size_t)(n0 + kq * 4 + r) * 16 + m] = acc[r];
}

// ---------------- KG2: layer-2 gather -> out -------------------------------
__global__ __launch_bounds__(256) void kg2(
    const int* __restrict__ rowptr, const int* __restrict__ colidx,
    const float* __restrict__ h2, const float* __restrict__ as2,
    const float* __restrict__ ad2, const float* __restrict__ b2,
    float* __restrict__ out, int N)
{
    const int d = blockIdx.x * 4 + (threadIdx.x >> 6);
    if (d >= N) return;
    const int lane = threadIdx.x & 63;
    const int j = lane & 15, g = lane >> 4;

    const float ad_d = ad2[d];
    float acc = 0.f, den = 0.f;
    const int i0 = __builtin_amdgcn_readfirstlane(rowptr[d]);
    const int i1 = __builtin_amdgcn_readfirstlane(rowptr[d + 1]);
    int i = i0 + g;
    for (; i + 4 < i1; i += 8) {
        int s0 = colidx[i];
        int s1 = colidx[i + 4];
        float a0 = as2[s0];
        float a1 = as2[s1];
        float v0 = h2[(s0 << 4) + j];
        float v1 = h2[(s1 << 4) + j];
        float w0 = __expf(leaky02(a0 + ad_d));
        float w1 = __expf(leaky02(a1 + ad_d));
        acc = fmaf(w0, v0, acc);
        acc = fmaf(w1, v1, acc);
        den += w0 + w1;
    }
    for (; i < i1; i += 4) {
        int s = colidx[i];
        float w = __expf(leaky02(as2[s] + ad_d));
        acc = fmaf(w, h2[(s << 4) + j], acc);
        den += w;
    }
    acc += __shfl_xor(acc, 16); acc += __shfl_xor(acc, 32);
    den += __shfl_xor(den, 16); den += __shfl_xor(den, 32);

    const float wself = __expf(leaky02(as2[d] + ad_d));
    acc = fmaf(wself, h2[(d << 4) + j], acc);
    den += wself;
    if (g == 0) out[(d << 4) + j] = acc / den + b2[j];
}

extern "C" void kernel_launch(void* const* d_in, const int* in_sizes, int n_in,
                              void* d_out, int out_size, void* d_ws, size_t ws_size,
                              hipStream_t stream) {
    const float* x    = (const float*)d_in[0];
    const int*   ei   = (const int*)d_in[1];
    const float* W1   = (const float*)d_in[2];
    const float* ats1 = (const float*)d_in[3];
    const float* atd1 = (const float*)d_in[4];
    const float* b1   = (const float*)d_in[5];
    const float* W2   = (const float*)d_in[6];
    const float* ats2 = (const float*)d_in[7];
    const float* atd2 = (const float*)d_in[8];
    const float* b2   = (const float*)d_in[9];
    float* out = (float*)d_out;
    const int N = in_sizes[0] / 128;
    const int E = in_sizes[1] / 2;

    u16* h1b   = (u16*)d_ws;                        // 128N u16
    u16* x2b   = h1b + (size_t)N * 128;             // 128N u16
    float* fb  = (float*)(x2b + (size_t)N * 128);
    float* as1 = fb;                                // 4N
    float* ad1 = as1 + (size_t)N * 4;               // 4N
    float* h2  = ad1 + (size_t)N * 4;               // 16N
    float* as2 = h2 + (size_t)N * 16;               // N
    float* ad2 = as2 + N;                           // N
    float* u   = ad2 + N;                           // 128
    float* v   = u + 128;                           // 128
    u16* w2tb  = (u16*)(v + 128);                   // 2048 u16
    int* deg    = (int*)(w2tb + 2048);              // N
    int* rowptr = deg + N;                          // N+1
    int* bsum   = rowptr + N + 1;                   // 128
    int* colidx = bsum + 128;                       // E
    int* rank   = colidx + E;                       // E

    const int NB = (N + 1023) / 1024;

    hipMemsetAsync(deg, 0, (size_t)N * sizeof(int), stream);

    hipLaunchKernelGGL(k1_gemm, dim3((N + 127) / 128), dim3(256), 0, stream,
                       x, W1, ats1, atd1, h1b, as1, ad1, N);
    hipLaunchKernelGGL(kprep, dim3(1), dim3(128), 0, stream,
                       W2, ats2, atd2, u, v, w2tb);
    hipLaunchKernelGGL(khist, dim3((E + 255) / 256), dim3(256), 0, stream,
                       ei, deg, rank, E);
    hipLaunchKernelGGL(kscan1, dim3(NB), dim3(256), 0, stream,
                       deg, rowptr, bsum, N);
    hipLaunchKernelGGL(kscan2, dim3(1), dim3(128), 0, stream, bsum, NB);
    hipLaunchKernelGGL(kscan3, dim3(NB), dim3(256), 0, stream,
                       rowptr, bsum, N, E);
    hipLaunchKernelGGL(kscatter, dim3((E + 255) / 256), dim3(256), 0, stream,
                       ei, rowptr, rank, colidx, E);
    hipLaunchKernelGGL(kg1, dim3((N + 3) / 4), dim3(256), 0, stream,
                       rowptr, colidx, h1b, as1, ad1, b1, u, v,
                       x2b, as2, ad2, N);
    hipLaunchKernelGGL(kh2, dim3((N + 63) / 64), dim3(256), 0, stream,
                       x2b, w2tb, h2, N);
    hipLaunchKernelGGL(kg2, dim3((N + 3) / 4), dim3(256), 0, stream,
                       rowptr, colidx, h2, as2, ad2, b2, out, N);
}

// Round 6
// 379.551 us; speedup vs baseline: 1.5042x; 1.1305x over previous
//
#include <hip/hip_runtime.h>
#include <hip/hip_bf16.h>
#include <math.h>

// GAT 2-layer. Round 6: k1 fp32-VALU GEMM replaced by MFMA bf16 hi/lo-split
// GEMM (fp32-equivalent accuracy): h1 = x@W1 via xh*wh + xh*wl + xl*wh.
// W1 pre-swizzled into B-fragment order (kprep1), staged in LDS. h2 stored
// bf16; kg2 uses 8 edge-groups x 2ch/lane. CSR gather pipeline unchanged.

typedef unsigned short u16;
typedef unsigned int u32;
typedef __attribute__((ext_vector_type(8))) short bf16x8;
typedef __attribute__((ext_vector_type(4))) float f32x4;

__device__ __forceinline__ float leaky02(float e) { return e >= 0.f ? e : 0.2f * e; }
__device__ __forceinline__ float eluf(float v) { return v > 0.f ? v : expm1f(v); }
__device__ __forceinline__ u16 f2bf(float f) {
    u32 u = __float_as_uint(f);
    u += 0x7fff + ((u >> 16) & 1);          // RNE
    return (u16)(u >> 16);
}
__device__ __forceinline__ float bf2f(u16 u) {
    return __uint_as_float(((u32)u) << 16);
}

// ---------------- kprep1: W1 -> B-fragment-ordered bf16 hi/lo --------------
// frag idx: ((ct*4+q)*64 + lane)*8 + j  maps to  W1[k=q*32+(lane>>4)*8+j]
//                                               [n=ct*16+(lane&15)]
__global__ __launch_bounds__(256) void kprep1(
    const float* __restrict__ W1, u16* __restrict__ w1fh, u16* __restrict__ w1fl)
{
    const int tid = threadIdx.x;
    for (int i = 0; i < 64; ++i) {
        int idx = i * 256 + tid;            // [0,16384)
        int j = idx & 7, l = (idx >> 3) & 63, q = (idx >> 9) & 3, ct = idx >> 11;
        int k = q * 32 + (l >> 4) * 8 + j;
        int n = ct * 16 + (l & 15);
        float w = W1[k * 128 + n];
        u16 hv = f2bf(w);
        w1fh[idx] = hv;
        w1fl[idx] = f2bf(w - bf2f(hv));
    }
}

// ---------------- KH1: h1 = x @ W1 via MFMA (hi/lo split) + att dots -------
// Block 256 = 4 waves, 16 rows/wave, 64 rows/block. LDS holds W1 frags.
__global__ __launch_bounds__(256, 2) void kh1(
    const float* __restrict__ x, const u16* __restrict__ w1fh,
    const u16* __restrict__ w1fl,
    const float* __restrict__ att_s, const float* __restrict__ att_d,
    u16* __restrict__ h1b, float* __restrict__ as1, float* __restrict__ ad1,
    int N)
{
    __shared__ u16 lh[16384];
    __shared__ u16 ll[16384];
    const int tid = threadIdx.x;
    #pragma unroll
    for (int i = 0; i < 8; ++i) {
        int fi = (tid + i * 256) * 8;
        *(uint4*)&lh[fi] = *(const uint4*)&w1fh[fi];
        *(uint4*)&ll[fi] = *(const uint4*)&w1fl[fi];
    }
    const int wv = tid >> 6, lane = tid & 63;
    const int base = blockIdx.x * 64 + wv * 16;
    const int m = lane & 15, quad = lane >> 4;

    // A fragments: row = base+m, k = q*32 + quad*8 + j (hi/lo split)
    int arow = base + m;
    if (arow >= N) arow = 0;
    const float* xr = &x[(size_t)arow * 128 + quad * 8];
    bf16x8 ah[4], al[4];
    #pragma unroll
    for (int q = 0; q < 4; ++q) {
        float4 f0 = *(const float4*)&xr[q * 32];
        float4 f1 = *(const float4*)&xr[q * 32 + 4];
        float fv[8] = {f0.x, f0.y, f0.z, f0.w, f1.x, f1.y, f1.z, f1.w};
        union { u16 us[8]; bf16x8 v; } hh, lu;
        #pragma unroll
        for (int j = 0; j < 8; ++j) {
            u16 h = f2bf(fv[j]);
            hh.us[j] = h;
            lu.us[j] = f2bf(fv[j] - bf2f(h));
        }
        ah[q] = hh.v; al[q] = lu.v;
    }
    __syncthreads();

    // D rows this lane owns: base + quad*4 + r ; D col within tile = m
    #pragma unroll
    for (int h = 0; h < 4; ++h) {
        float sp[4] = {0.f, 0.f, 0.f, 0.f};
        float dp[4] = {0.f, 0.f, 0.f, 0.f};
        #pragma unroll
        for (int sub = 0; sub < 2; ++sub) {
            const int ct = h * 2 + sub;
            f32x4 acc = {0.f, 0.f, 0.f, 0.f};
            #pragma unroll
            for (int q = 0; q < 4; ++q) {
                const int off = ((ct * 4 + q) * 64 + lane) * 8;
                bf16x8 bh = *(const bf16x8*)&lh[off];
                bf16x8 bl = *(const bf16x8*)&ll[off];
                acc = __builtin_amdgcn_mfma_f32_16x16x32_bf16(ah[q], bh, acc, 0, 0, 0);
                acc = __builtin_amdgcn_mfma_f32_16x16x32_bf16(al[q], bh, acc, 0, 0, 0);
                acc = __builtin_amdgcn_mfma_f32_16x16x32_bf16(ah[q], bl, acc, 0, 0, 0);
            }
            const float cs = att_s[h * 32 + sub * 16 + m];
            const float cd = att_d[h * 32 + sub * 16 + m];
            #pragma unroll
            for (int r = 0; r < 4; ++r) {
                int rr = base + quad * 4 + r;
                if (rr < N) h1b[(size_t)rr * 128 + ct * 16 + m] = f2bf(acc[r]);
                sp[r] = fmaf(acc[r], cs, sp[r]);
                dp[r] = fmaf(acc[r], cd, dp[r]);
            }
        }
        #pragma unroll
        for (int r = 0; r < 4; ++r) {
            sp[r] += __shfl_xor(sp[r], 1); sp[r] += __shfl_xor(sp[r], 2);
            sp[r] += __shfl_xor(sp[r], 4); sp[r] += __shfl_xor(sp[r], 8);
            dp[r] += __shfl_xor(dp[r], 1); dp[r] += __shfl_xor(dp[r], 2);
            dp[r] += __shfl_xor(dp[r], 4); dp[r] += __shfl_xor(dp[r], 8);
        }
        if (m == 0) {
            #pragma unroll
            for (int r = 0; r < 4; ++r) {
                int rr = base + quad * 4 + r;
                if (rr < N) {
                    as1[rr * 4 + h] = sp[r];
                    ad1[rr * 4 + h] = dp[r];
                }
            }
        }
    }
}

// ---------------- kprep: u = W2@ats2, v = W2@atd2, w2tb = W2^T (bf16) ------
__global__ __launch_bounds__(128) void kprep(
    const float* __restrict__ W2, const float* __restrict__ ats2,
    const float* __restrict__ atd2,
    float* __restrict__ u, float* __restrict__ v, u16* __restrict__ w2tb)
{
    const int c = threadIdx.x;      // 0..127
    float su = 0.f, sv = 0.f;
    #pragma unroll
    for (int j = 0; j < 16; ++j) {
        float w = W2[c * 16 + j];
        su = fmaf(w, ats2[j], su);
        sv = fmaf(w, atd2[j], sv);
        w2tb[j * 128 + c] = f2bf(w);   // transposed: [j][c]
    }
    u[c] = su; v[c] = sv;
}

// ---------------- CSR build ------------------------------------------------
__global__ __launch_bounds__(256) void khist(
    const int* __restrict__ ei, int* __restrict__ deg,
    int* __restrict__ rank, int E)
{
    int e = blockIdx.x * 256 + threadIdx.x;
    if (e < E) rank[e] = atomicAdd(&deg[ei[E + e]], 1);
}

__global__ __launch_bounds__(256) void kscan1(
    const int* __restrict__ deg, int* __restrict__ rowptr,
    int* __restrict__ bsum, int N)
{
    __shared__ int lds[256];
    const int t = threadIdx.x;
    const int base = blockIdx.x * 1024 + t * 4;
    int v[4];
    int s = 0;
    #pragma unroll
    for (int j = 0; j < 4; ++j) {
        v[j] = (base + j < N) ? deg[base + j] : 0;
        s += v[j];
    }
    lds[t] = s;
    __syncthreads();
    for (int off = 1; off < 256; off <<= 1) {
        int y = (t >= off) ? lds[t - off] : 0;
        __syncthreads();
        lds[t] += y;
        __syncthreads();
    }
    int run = lds[t] - s;
    #pragma unroll
    for (int j = 0; j < 4; ++j) {
        if (base + j < N) rowptr[base + j] = run;
        run += v[j];
    }
    if (t == 255) bsum[blockIdx.x] = lds[255];
}

__global__ __launch_bounds__(128) void kscan2(int* __restrict__ bsum, int NB)
{
    __shared__ int lds[128];
    const int t = threadIdx.x;
    int v = (t < NB) ? bsum[t] : 0;
    lds[t] = v;
    __syncthreads();
    for (int off = 1; off < 128; off <<= 1) {
        int y = (t >= off) ? lds[t - off] : 0;
        __syncthreads();
        lds[t] += y;
        __syncthreads();
    }
    if (t < NB) bsum[t] = lds[t] - v;
}

__global__ __launch_bounds__(256) void kscan3(
    int* __restrict__ rowptr, const int* __restrict__ bsum, int N, int E)
{
    const int base = blockIdx.x * 1024 + threadIdx.x * 4;
    const int add = bsum[blockIdx.x];
    #pragma unroll
    for (int j = 0; j < 4; ++j)
        if (base + j < N) rowptr[base + j] += add;
    if (blockIdx.x == 0 && threadIdx.x == 0) rowptr[N] = E;
}

__global__ __launch_bounds__(256) void kscatter(
    const int* __restrict__ ei, const int* __restrict__ rowptr,
    const int* __restrict__ rank, int* __restrict__ colidx, int E)
{
    int e = blockIdx.x * 256 + threadIdx.x;
    if (e >= E) return;
    colidx[rowptr[ei[E + e]] + rank[e]] = ei[e];
}

// ---------------- KG1: layer-1 gather + elu -> x2 (bf16) + as2/ad2 ---------
__global__ __launch_bounds__(256) void kg1(
    const int* __restrict__ rowptr, const int* __restrict__ colidx,
    const u16* __restrict__ h1b, const float* __restrict__ as1,
    const float* __restrict__ ad1, const float* __restrict__ b1,
    const float* __restrict__ u, const float* __restrict__ v,
    u16* __restrict__ x2b, float* __restrict__ as2, float* __restrict__ ad2,
    int N)
{
    const int d = blockIdx.x * 4 + (threadIdx.x >> 6);
    if (d >= N) return;
    const int lane = threadIdx.x & 63;
    const int c = lane * 2;
    const int head = lane >> 4;

    const float ad_d = ad1[d * 4 + head];
    const float as_d = as1[d * 4 + head];

    const float wself = __expf(leaky02(as_d + ad_d));
    u32 hd = *(const u32*)&h1b[(d << 7) + c];
    float accx = wself * bf2f((u16)hd);
    float accy = wself * bf2f((u16)(hd >> 16));
    float den = wself;

    const int i0 = __builtin_amdgcn_readfirstlane(rowptr[d]);
    const int i1 = __builtin_amdgcn_readfirstlane(rowptr[d + 1]);
    int i = i0;
    for (; i + 8 <= i1; i += 8) {
        int s0 = colidx[i + 0];
        int s1 = colidx[i + 1];
        int s2 = colidx[i + 2];
        int s3 = colidx[i + 3];
        int s4 = colidx[i + 4];
        int s5 = colidx[i + 5];
        int s6 = colidx[i + 6];
        int s7 = colidx[i + 7];
        float a0 = as1[s0 * 4 + head];
        float a1 = as1[s1 * 4 + head];
        float a2 = as1[s2 * 4 + head];
        float a3 = as1[s3 * 4 + head];
        float a4 = as1[s4 * 4 + head];
        float a5 = as1[s5 * 4 + head];
        float a6 = as1[s6 * 4 + head];
        float a7 = as1[s7 * 4 + head];
        u32 v0 = *(const u32*)&h1b[(s0 << 7) + c];
        u32 v1 = *(const u32*)&h1b[(s1 << 7) + c];
        u32 v2 = *(const u32*)&h1b[(s2 << 7) + c];
        u32 v3 = *(const u32*)&h1b[(s3 << 7) + c];
        u32 v4 = *(const u32*)&h1b[(s4 << 7) + c];
        u32 v5 = *(const u32*)&h1b[(s5 << 7) + c];
        u32 v6 = *(const u32*)&h1b[(s6 << 7) + c];
        u32 v7 = *(const u32*)&h1b[(s7 << 7) + c];
        float w0 = __expf(leaky02(a0 + ad_d));
        float w1 = __expf(leaky02(a1 + ad_d));
        float w2 = __expf(leaky02(a2 + ad_d));
        float w3 = __expf(leaky02(a3 + ad_d));
        float w4 = __expf(leaky02(a4 + ad_d));
        float w5 = __expf(leaky02(a5 + ad_d));
        float w6 = __expf(leaky02(a6 + ad_d));
        float w7 = __expf(leaky02(a7 + ad_d));
        accx = fmaf(w0, bf2f((u16)v0), accx); accy = fmaf(w0, bf2f((u16)(v0 >> 16)), accy);
        accx = fmaf(w1, bf2f((u16)v1), accx); accy = fmaf(w1, bf2f((u16)(v1 >> 16)), accy);
        accx = fmaf(w2, bf2f((u16)v2), accx); accy = fmaf(w2, bf2f((u16)(v2 >> 16)), accy);
        accx = fmaf(w3, bf2f((u16)v3), accx); accy = fmaf(w3, bf2f((u16)(v3 >> 16)), accy);
        accx = fmaf(w4, bf2f((u16)v4), accx); accy = fmaf(w4, bf2f((u16)(v4 >> 16)), accy);
        accx = fmaf(w5, bf2f((u16)v5), accx); accy = fmaf(w5, bf2f((u16)(v5 >> 16)), accy);
        accx = fmaf(w6, bf2f((u16)v6), accx); accy = fmaf(w6, bf2f((u16)(v6 >> 16)), accy);
        accx = fmaf(w7, bf2f((u16)v7), accx); accy = fmaf(w7, bf2f((u16)(v7 >> 16)), accy);
        den += ((w0 + w1) + (w2 + w3)) + ((w4 + w5) + (w6 + w7));
    }
    for (; i < i1; ++i) {
        int s = colidx[i];
        float a = as1[s * 4 + head];
        u32 hv = *(const u32*)&h1b[(s << 7) + c];
        float w = __expf(leaky02(a + ad_d));
        accx = fmaf(w, bf2f((u16)hv), accx);
        accy = fmaf(w, bf2f((u16)(hv >> 16)), accy);
        den += w;
    }

    const float inv = 1.f / den;
    const float2 bv = *(const float2*)&b1[c];
    const float x2a = eluf(fmaf(accx, inv, bv.x));
    const float x2c = eluf(fmaf(accy, inv, bv.y));

    u32 pk = ((u32)f2bf(x2c) << 16) | (u32)f2bf(x2a);
    *(u32*)&x2b[(d << 7) + c] = pk;

    const float2 uv = *(const float2*)&u[c];
    const float2 vv = *(const float2*)&v[c];
    float sA = fmaf(x2a, uv.x, x2c * uv.y);
    float sB = fmaf(x2a, vv.x, x2c * vv.y);
    #pragma unroll
    for (int m = 1; m < 64; m <<= 1) {
        sA += __shfl_xor(sA, m);
        sB += __shfl_xor(sB, m);
    }
    if (lane == 0) { as2[d] = sA; ad2[d] = sB; }
}

// ---------------- KH2: h2 = x2 @ W2 via MFMA (bf16 out) --------------------
__global__ __launch_bounds__(256) void kh2(
    const u16* __restrict__ x2b, const u16* __restrict__ w2tb,
    u16* __restrict__ h2b, int N)
{
    const int wv = threadIdx.x >> 6, lane = threadIdx.x & 63;
    const int n0 = blockIdx.x * 64 + wv * 16;
    if (n0 >= N) return;
    const int m = lane & 15;
    const int kq = lane >> 4;
    bf16x8 bfr[4];
    #pragma unroll
    for (int q = 0; q < 4; ++q)
        bfr[q] = *(const bf16x8*)&w2tb[m * 128 + q * 32 + kq * 8];

    int ar = n0 + m;
    if (ar >= N) ar = N - 1;
    const u16* arow = &x2b[((size_t)ar << 7) + kq * 8];
    f32x4 acc = {0.f, 0.f, 0.f, 0.f};
    #pragma unroll
    for (int q = 0; q < 4; ++q) {
        bf16x8 af = *(const bf16x8*)&arow[q * 32];
        acc = __builtin_amdgcn_mfma_f32_16x16x32_bf16(af, bfr[q], acc, 0, 0, 0);
    }
    #pragma unroll
    for (int r = 0; r < 4; ++r) {
        int rr = n0 + kq * 4 + r;
        if (rr < N) h2b[((size_t)rr << 4) + m] = f2bf(acc[r]);
    }
}

// ---------------- KG2: layer-2 gather -> out -------------------------------
// One wave per node: 8 edge-groups x 8 lanes, 2 channels/lane (bf16 h2).
__global__ __launch_bounds__(256) void kg2(
    const int* __restrict__ rowptr, const int* __restrict__ colidx,
    const u16* __restrict__ h2b, const float* __restrict__ as2,
    const float* __restrict__ ad2, const float* __restrict__ b2,
    float* __restrict__ out, int N)
{
    const int d = blockIdx.x * 4 + (threadIdx.x >> 6);
    if (d >= N) return;
    const int lane = threadIdx.x & 63;
    const int ch = lane & 7, g = lane >> 3;   // channels 2ch,2ch+1

    const float ad_d = ad2[d];
    float acc0 = 0.f, acc1 = 0.f, den = 0.f;
    const int i0 = __builtin_amdgcn_readfirstlane(rowptr[d]);
    const int i1 = __builtin_amdgcn_readfirstlane(rowptr[d + 1]);
    int i = i0 + g;
    for (; i + 8 < i1; i += 16) {
        int s0 = colidx[i];
        int s1 = colidx[i + 8];
        float a0 = as2[s0];
        float a1 = as2[s1];
        u32 v0 = *(const u32*)&h2b[(s0 << 4) + ch * 2];
        u32 v1 = *(const u32*)&h2b[(s1 << 4) + ch * 2];
        float w0 = __expf(leaky02(a0 + ad_d));
        float w1 = __expf(leaky02(a1 + ad_d));
        acc0 = fmaf(w0, bf2f((u16)v0), acc0);
        acc1 = fmaf(w0, bf2f((u16)(v0 >> 16)), acc1);
        acc0 = fmaf(w1, bf2f((u16)v1), acc0);
        acc1 = fmaf(w1, bf2f((u16)(v1 >> 16)), acc1);
        den += w0 + w1;
    }
    for (; i < i1; i += 8) {
        int s = colidx[i];
        float w = __expf(leaky02(as2[s] + ad_d));
        u32 hv = *(const u32*)&h2b[(s << 4) + ch * 2];
        acc0 = fmaf(w, bf2f((u16)hv), acc0);
        acc1 = fmaf(w, bf2f((u16)(hv >> 16)), acc1);
        den += w;
    }
    acc0 += __shfl_xor(acc0, 8); acc0 += __shfl_xor(acc0, 16); acc0 += __shfl_xor(acc0, 32);
    acc1 += __shfl_xor(acc1, 8); acc1 += __shfl_xor(acc1, 16); acc1 += __shfl_xor(acc1, 32);
    den  += __shfl_xor(den, 8);  den  += __shfl_xor(den, 16);  den  += __shfl_xor(den, 32);

    const float wself = __expf(leaky02(as2[d] + ad_d));
    u32 hd = *(const u32*)&h2b[(d << 4) + ch * 2];
    acc0 = fmaf(wself, bf2f((u16)hd), acc0);
    acc1 = fmaf(wself, bf2f((u16)(hd >> 16)), acc1);
    den += wself;
    if (g == 0) {
        float2 ov = {acc0 / den + b2[ch * 2], acc1 / den + b2[ch * 2 + 1]};
        *(float2*)&out[(d << 4) + ch * 2] = ov;
    }
}

extern "C" void kernel_launch(void* const* d_in, const int* in_sizes, int n_in,
                              void* d_out, int out_size, void* d_ws, size_t ws_size,
                              hipStream_t stream) {
    const float* x    = (const float*)d_in[0];
    const int*   ei   = (const int*)d_in[1];
    const float* W1   = (const float*)d_in[2];
    const float* ats1 = (const float*)d_in[3];
    const float* atd1 = (const float*)d_in[4];
    const float* b1   = (const float*)d_in[5];
    const float* W2   = (const float*)d_in[6];
    const float* ats2 = (const float*)d_in[7];
    const float* atd2 = (const float*)d_in[8];
    const float* b2   = (const float*)d_in[9];
    float* out = (float*)d_out;
    const int N = in_sizes[0] / 128;
    const int E = in_sizes[1] / 2;

    u16* h1b   = (u16*)d_ws;                        // 128N u16
    u16* x2b   = h1b + (size_t)N * 128;             // 128N u16
    float* fb  = (float*)(x2b + (size_t)N * 128);
    float* as1 = fb;                                // 4N
    float* ad1 = as1 + (size_t)N * 4;               // 4N
    u16* h2b   = (u16*)(ad1 + (size_t)N * 4);       // 16N u16
    float* as2 = (float*)(h2b + (size_t)N * 16);    // N
    float* ad2 = as2 + N;                           // N
    float* u   = ad2 + N;                           // 128
    float* v   = u + 128;                           // 128
    u16* w2tb  = (u16*)(v + 128);                   // 2048 u16
    u16* w1fh  = w2tb + 2048;                       // 16384 u16
    u16* w1fl  = w1fh + 16384;                      // 16384 u16
    int* deg    = (int*)(w1fl + 16384);             // N
    int* rowptr = deg + N;                          // N+1
    int* bsum   = rowptr + N + 1;                   // 128
    int* colidx = bsum + 128;                       // E
    int* rank   = colidx + E;                       // E

    const int NB = (N + 1023) / 1024;

    hipMemsetAsync(deg, 0, (size_t)N * sizeof(int), stream);

    hipLaunchKernelGGL(kprep1, dim3(1), dim3(256), 0, stream, W1, w1fh, w1fl);
    hipLaunchKernelGGL(kprep, dim3(1), dim3(128), 0, stream,
                       W2, ats2, atd2, u, v, w2tb);
    hipLaunchKernelGGL(kh1, dim3((N + 63) / 64), dim3(256), 0, stream,
                       x, w1fh, w1fl, ats1, atd1, h1b, as1, ad1, N);
    hipLaunchKernelGGL(khist, dim3((E + 255) / 256), dim3(256), 0, stream,
                       ei, deg, rank, E);
    hipLaunchKernelGGL(kscan1, dim3(NB), dim3(256), 0, stream,
                       deg, rowptr, bsum, N);
    hipLaunchKernelGGL(kscan2, dim3(1), dim3(128), 0, stream, bsum, NB);
    hipLaunchKernelGGL(kscan3, dim3(NB), dim3(256), 0, stream,
                       rowptr, bsum, N, E);
    hipLaunchKernelGGL(kscatter, dim3((E + 255) / 256), dim3(256), 0, stream,
                       ei, rowptr, rank, colidx, E);
    hipLaunchKernelGGL(kg1, dim3((N + 3) / 4), dim3(256), 0, stream,
                       rowptr, colidx, h1b, as1, ad1, b1, u, v,
                       x2b, as2, ad2, N);
    hipLaunchKernelGGL(kh2, dim3((N + 63) / 64), dim3(256), 0, stream,
                       x2b, w2tb, h2b, N);
    hipLaunchKernelGGL(kg2, dim3((N + 3) / 4), dim3(256), 0, stream,
                       rowptr, colidx, h2b, as2, ad2, b2, out, N);
}